// Round 7
// baseline (259.218 us; speedup 1.0000x reference)
//
#include <hip/hip_runtime.h>
#include <hip/hip_bf16.h>
#include <hip/hip_cooperative_groups.h>

namespace cg = cooperative_groups;

#define BB 4      // batch
#define SS 1023   // source length = 2T-1
#define TT 512    // window length
#define CC 1024   // embed dim
#define DD 64     // head size
#define NROW (BB*SS)    // 4092
#define NROWP 4096      // padded kT row stride: kT[d][b*1024 + s]

typedef float f4 __attribute__((ext_vector_type(4)));
typedef float f2 __attribute__((ext_vector_type(2)));
typedef short bf16x8 __attribute__((ext_vector_type(8)));
typedef short s4 __attribute__((ext_vector_type(4)));
typedef float f32x4 __attribute__((ext_vector_type(4)));

// RTN bf16 split: v ~= hi + lo (packed u32 lo<<16|hi).
// SESSION INVARIANT: this split + ALL FOUR MFMA products is the only
// verified-passing config (r12/r13: 0.0156). Manual trunc/half-up splits
// with al*bl dropped fail deterministically at ~0.18 (r14/r15/r16) for
// reasons not visible at source level. Do not "optimize" this again.
__device__ __forceinline__ unsigned split_rtn(float v) {
    const unsigned u  = __builtin_bit_cast(unsigned, v);
    const unsigned r  = u + 0x7FFFu + ((u >> 16) & 1u);
    const unsigned hi = r >> 16;
    const float hif   = __builtin_bit_cast(float, r & 0xFFFF0000u);
    const float res   = v - hif;
    const unsigned u2 = __builtin_bit_cast(unsigned, res);
    const unsigned r2 = u2 + 0x7FFFu + ((u2 >> 16) & 1u);
    return (r2 & 0xFFFF0000u) | hi;                    // lo<<16 | hi
}

// ---------------------------------------------------------------------------
// MEGA-KERNEL: wsplit -> grid.sync -> proj (2 units/block) -> grid.sync ->
// attn (r6-verbatim). 256 blocks x 512 threads, cooperative launch,
// 128 KB LDS union (proj: 2x{lh,ll} 64 KB halves; attn: ~68 KB struct).
// All inner arithmetic byte-identical to the r4/r5/r6-verified kernels —
// only launch structure and LDS placement changed.
// ---------------------------------------------------------------------------
__global__ __launch_bounds__(512, 1) void mega_kernel(
    const float* __restrict__ x,
    const float* __restrict__ Wk,
    const float* __restrict__ Wv,
    const float* __restrict__ Wq,
    const float* __restrict__ bias,   // [DD][TT]
    float* __restrict__ kT,           // [DD][NROWP] padded
    float* __restrict__ vbuf,         // [NROW][DD]
    float* __restrict__ qbuf,         // [BB*TT][DD]
    unsigned short* __restrict__ bwh,
    unsigned short* __restrict__ bwl,
    float* __restrict__ out)          // [BB*TT][DD]
{
    __shared__ __align__(16) union SMem {
        struct {                                   // proj phase: 128 KB
            unsigned short lh[2][16 * 1024];       // per-half hi plane, 32 KB
            unsigned short ll[2][16 * 1024];       // per-half lo plane, 32 KB
        } p;
        struct {                                   // attn phase: ~68 KB
            float qsT[DD][8];                      // [d][m]    2 KB
            float part[2][8][TT];                  // [h][m][t] 32 KB
            float weiT[TT][9];                     // padded,   18 KB
            float invs[8];
            float partial[8][8][DD];               // 16 KB
        } a;
    } sm;

    const int tid  = threadIdx.x;
    const int lane = tid & 63;
    const int wv   = tid >> 6;          // 0..7
    cg::grid_group grid = cg::this_grid();

    // ======================= phase W: wsplit (verbatim) ====================
    {
        const int gw = blockIdx.x * 8 + wv;     // global wave id
        if (gw < 384) {
            const int f    = gw;                // 0..383
            const int p    = f >> 7;
            const int rem  = f & 127;
            const int nsub = rem >> 5;
            const int ks   = rem & 31;
            const int quad = lane >> 4, l4 = lane & 15;
            const float* W = (p == 0) ? Wk : (p == 1) ? Wv : Wq;
            const int n = nsub * 16 + l4;

            bf16x8 h, l;
#pragma unroll
            for (int j = 0; j < 8; ++j) {
                const int k = ks * 32 + quad * 8 + j;
                const unsigned hl = split_rtn(W[k * DD + n]);
                h[j] = (short)(hl & 0xFFFFu);
                l[j] = (short)(hl >> 16);
            }
            ((bf16x8*)bwh)[f * 64 + lane] = h;
            ((bf16x8*)bwl)[f * 64 + lane] = l;
        }
    }
    __threadfence();
    grid.sync();

    // ================= phase P: proj, 2 units per block ====================
    // super-unit su hosts units su*2 (waves 0-3) and su*2+1 (waves 4-7);
    // inner code byte-identical to the r4-verified proj_fused_kernel.
    for (int su = blockIdx.x; su < 384; su += 256) {
        const int half = wv >> 2;               // 0 or 1
        const int unit = su * 2 + half;         // 0..767
        const int p    = unit % 3;
        const int mt   = unit / 3;              // 0..255
        const int bs0  = mt * 16;
        const int ltid = tid & 255;             // 0..255 within half
        unsigned short* lh = sm.p.lh[half];
        unsigned short* ll = sm.p.ll[half];

        // ---- phase A: stage + split x tile ----
        {
            const int k = ltid * 4;             // 0..1020
#pragma unroll 4
            for (int i = 0; i < 16; ++i) {
                int arow = bs0 + i; if (arow > NROW - 1) arow = NROW - 1;
                const f4 xv = *(const f4*)(x + (size_t)arow * CC + k);
                s4 h, l;
#pragma unroll
                for (int j = 0; j < 4; ++j) {
                    const unsigned hl = split_rtn(xv[j]);
                    h[j] = (short)(hl & 0xFFFFu);
                    l[j] = (short)(hl >> 16);
                }
                const int idx = i * 1024 + (k ^ ((i & 7) << 3));
                *(s4*)&lh[idx] = h;
                *(s4*)&ll[idx] = l;
            }
        }
        __syncthreads();

        // ---- phase B: MFMA, wave (within half) w = nsub ----
        {
            const int llane = ltid & 63;
            const int w     = ltid >> 6;        // nsub 0..3
            const int quad  = llane >> 4, l4 = llane & 15;

            const bf16x8* bh = (const bf16x8*)bwh
                             + (size_t)((p * 4 + w) * 32) * 64 + llane;
            const bf16x8* bl = (const bf16x8*)bwl
                             + (size_t)((p * 4 + w) * 32) * 64 + llane;

            const int rbase = l4 * 1024;
            const int kxor  = (l4 & 7) << 3;

            f32x4 acc = {0.f, 0.f, 0.f, 0.f};
#pragma unroll 4
            for (int ks = 0; ks < 32; ++ks) {
                const int k0 = ks * 32 + quad * 8;
                const bf16x8 ah = *(const bf16x8*)&lh[rbase + (k0 ^ kxor)];
                const bf16x8 al = *(const bf16x8*)&ll[rbase + (k0 ^ kxor)];
                const bf16x8 bhn = bh[ks * 64];
                const bf16x8 bln = bl[ks * 64];
                acc = __builtin_amdgcn_mfma_f32_16x16x32_bf16(ah, bhn, acc, 0, 0, 0);
                acc = __builtin_amdgcn_mfma_f32_16x16x32_bf16(ah, bln, acc, 0, 0, 0);
                acc = __builtin_amdgcn_mfma_f32_16x16x32_bf16(al, bhn, acc, 0, 0, 0);
                acc = __builtin_amdgcn_mfma_f32_16x16x32_bf16(al, bln, acc, 0, 0, 0);
            }

            // ---- epilogue: D[row=quad*4+reg][col=l4], d = w*16 + l4 ----
            const int d = w * 16 + l4;
#pragma unroll
            for (int reg = 0; reg < 4; ++reg) {
                const int bs = bs0 + quad * 4 + reg;
                if (bs < NROW) {
                    const float val = acc[reg];
                    const int b = bs / SS, ss = bs - b * SS;
                    if (p == 0) {
                        kT[(size_t)d * NROWP + b * 1024 + ss] = val;   // padded
                    } else if (p == 1) {
                        vbuf[(size_t)bs * DD + d] = val;
                    } else {
                        if (ss >= TT - 1)
                            qbuf[((size_t)b * TT + (ss - (TT - 1))) * DD + d] = val;
                    }
                }
            }
        }
        __syncthreads();    // LDS reuse guard before next super-unit
    }
    __threadfence();
    grid.sync();

    // ================= phase T: attention (r6-verbatim) ====================
    {
        const int blk = blockIdx.x;         // 0..255
        const int b   = blk >> 6;
        const int w0  = (blk & 63) * 8;

        {
            const int m = tid >> 6, dd = tid & 63;
            sm.a.qsT[dd][m] = qbuf[((size_t)b * TT + w0 + m) * DD + dd];
        }
        __syncthreads();

        // ---- phase 1: q.k (banded) + q.bias; 16 logits/thread ----
        {
            const int h = tid >> 8, p = tid & 255;
            const int t0 = 2 * p;
            const float* kcol = kT + (size_t)(32 * h) * NROWP + b * 1024 + w0 + t0;
            const float* bp   = bias + (size_t)(32 * h) * TT + t0;
            float am[8][2];
#pragma unroll
            for (int m = 0; m < 8; ++m) { am[m][0] = 0.f; am[m][1] = 0.f; }
#pragma unroll 4
            for (int i = 0; i < 32; ++i) {
                const float* kr = kcol + (size_t)i * NROWP;
                const f2 k01 = *(const f2*)kr;
                const f2 k23 = *(const f2*)(kr + 2);
                const f2 k45 = *(const f2*)(kr + 4);
                const f2 k67 = *(const f2*)(kr + 6);
                const float k8 = kr[8];
                const f2 bv = *(const f2*)(bp + (size_t)i * TT);
                const f4 qA = *(const f4*)&sm.a.qsT[32 * h + i][0];
                const f4 qB = *(const f4*)&sm.a.qsT[32 * h + i][4];
                const float kk[9] = {k01[0], k01[1], k23[0], k23[1],
                                     k45[0], k45[1], k67[0], k67[1], k8};
                const float qq[8] = {qA[0], qA[1], qA[2], qA[3],
                                     qB[0], qB[1], qB[2], qB[3]};
#pragma unroll
                for (int m = 0; m < 8; ++m) {
                    // per-logit chain: k-fma then bias-fma (verified r5 order)
                    am[m][0] = fmaf(qq[m], kk[m],     am[m][0]);
                    am[m][0] = fmaf(qq[m], bv[0],     am[m][0]);
                    am[m][1] = fmaf(qq[m], kk[m + 1], am[m][1]);
                    am[m][1] = fmaf(qq[m], bv[1],     am[m][1]);
                }
            }
#pragma unroll
            for (int m = 0; m < 8; ++m)
                *(f2*)&sm.a.part[h][m][t0] = (f2){am[m][0], am[m][1]};
        }
        __syncthreads();

        // ---- softmax: wave wv owns window m = wv; 8 t per lane ----
        {
            const int m = wv;
            float r[8];
#pragma unroll
            for (int j = 0; j < 8; ++j) {
                const int t = lane + 64 * j;
                r[j] = sm.a.part[0][m][t] + sm.a.part[1][m][t];
            }
            float mx = r[0];
#pragma unroll
            for (int j = 1; j < 8; ++j) mx = fmaxf(mx, r[j]);
#pragma unroll
            for (int off = 1; off < 64; off <<= 1)
                mx = fmaxf(mx, __shfl_xor(mx, off, 64));
            float sum = 0.f;
#pragma unroll
            for (int j = 0; j < 8; ++j) {
                const float e = __expf(r[j] - mx);
                sm.a.weiT[lane + 64 * j][m] = e;
                sum += e;
            }
#pragma unroll
            for (int off = 1; off < 64; off <<= 1)
                sum += __shfl_xor(sum, off, 64);
            if (lane == 0) sm.a.invs[m] = 1.f / sum;
        }
        __syncthreads();

        // ---- phase 2: PV, wave wv covers 64 t, sliding 8-reg v window ----
        {
            const int t0r = wv * 64;
            const float* vb = vbuf + ((size_t)b * SS + w0 + t0r) * DD + lane;
            float pm[8];
#pragma unroll
            for (int m = 0; m < 8; ++m) pm[m] = 0.f;
            float vvv[8];
#pragma unroll
            for (int m = 0; m < 7; ++m) vvv[m] = vb[(size_t)m * DD];
#pragma unroll 2
            for (int t = 0; t < 64; ++t) {
                vvv[7] = vb[(size_t)(t + 7) * DD];
                const float* wt = &sm.a.weiT[t0r + t][0];   // wave-uniform
#pragma unroll
                for (int m = 0; m < 8; ++m)
                    pm[m] = fmaf(wt[m], vvv[m], pm[m]);
#pragma unroll
                for (int m = 0; m < 7; ++m) vvv[m] = vvv[m + 1];
            }
#pragma unroll
            for (int m = 0; m < 8; ++m)
                sm.a.partial[wv][m][lane] = pm[m];
        }
        __syncthreads();

        // ---- final reduce + store ----
        {
            const int m = tid >> 6, dd = tid & 63;
            float o = 0.f;
#pragma unroll
            for (int j = 0; j < 8; ++j) o += sm.a.partial[j][m][dd];
            out[((size_t)b * TT + w0 + m) * DD + dd] = o * sm.a.invs[m];
        }
    }
}

// ---------------------------------------------------------------------------
extern "C" void kernel_launch(void* const* d_in, const int* in_sizes, int n_in,
                              void* d_out, int out_size, void* d_ws, size_t ws_size,
                              hipStream_t stream) {
    const float* x    = (const float*)d_in[0];
    const float* Wk   = (const float*)d_in[1];
    const float* Wv   = (const float*)d_in[2];
    const float* Wq   = (const float*)d_in[3];
    const float* bias = (const float*)d_in[4];
    float* out = (float*)d_out;

    char* ws = (char*)d_ws;
    float* kT             = (float*)(ws + 0);                 // 1 MB
    float* vbuf           = (float*)(ws + (2u  << 20));       // 1.05 MB
    float* qbuf           = (float*)(ws + (4u  << 20));       // 0.52 MB
    unsigned short* bwh   = (unsigned short*)(ws + (6u  << 20));  // 0.39 MB
    unsigned short* bwl   = (unsigned short*)(ws + (8u  << 20));  // 0.39 MB

    void* args[] = {
        (void*)&x, (void*)&Wk, (void*)&Wv, (void*)&Wq, (void*)&bias,
        (void*)&kT, (void*)&vbuf, (void*)&qbuf, (void*)&bwh, (void*)&bwl,
        (void*)&out
    };
    hipLaunchCooperativeKernel((const void*)mega_kernel,
                               dim3(256), dim3(512), args, 0, stream);
}

// Round 8
// 104.811 us; speedup vs baseline: 2.4732x; 2.4732x over previous
//
#include <hip/hip_runtime.h>
#include <hip/hip_bf16.h>

#define BB 4      // batch
#define SS 1023   // source length = 2T-1
#define TT 512    // window length
#define CC 1024   // embed dim
#define DD 64     // head size
#define NROW (BB*SS)    // 4092
#define NROWP 4096      // padded kT row stride: kT[d][b*1024 + s]

typedef float f4 __attribute__((ext_vector_type(4)));
typedef float f2 __attribute__((ext_vector_type(2)));
typedef short bf16x8 __attribute__((ext_vector_type(8)));
typedef short s4 __attribute__((ext_vector_type(4)));
typedef float f32x4 __attribute__((ext_vector_type(4)));

// RTN bf16 split: v ~= hi + lo (packed u32 lo<<16|hi).
// SESSION INVARIANT: this split + ALL FOUR MFMA products is the only
// verified-passing config (r12/r13: 0.0156). Manual trunc/half-up splits
// with al*bl dropped fail deterministically at ~0.18 (r14/r15/r16) for
// reasons not visible at source level. Do not "optimize" this again.
// SESSION NOTE r7: cooperative grid.sync() costs ~75us/sync at grid=256 on
// this chip (mega-kernel: 176us, VALUBusy 5.9%). Never fuse via grid.sync.
__device__ __forceinline__ unsigned split_rtn(float v) {
    const unsigned u  = __builtin_bit_cast(unsigned, v);
    const unsigned r  = u + 0x7FFFu + ((u >> 16) & 1u);
    const unsigned hi = r >> 16;
    const float hif   = __builtin_bit_cast(float, r & 0xFFFF0000u);
    const float res   = v - hif;
    const unsigned u2 = __builtin_bit_cast(unsigned, res);
    const unsigned r2 = u2 + 0x7FFFu + ((u2 >> 16) & 1u);
    return (r2 & 0xFFFF0000u) | hi;                    // lo<<16 | hi
}

// ---------------------------------------------------------------------------
// Kernel 1: split W{k,v,q} into B-fragment-ordered bf16 hi/lo (RTN).
// (verified r4/r5/r6 — unchanged)
// ---------------------------------------------------------------------------
__global__ __launch_bounds__(64) void wsplit_kernel(
    const float* __restrict__ Wk,
    const float* __restrict__ Wv,
    const float* __restrict__ Wq,
    unsigned short* __restrict__ bwh,
    unsigned short* __restrict__ bwl)
{
    const int f    = blockIdx.x;        // 0..383
    const int p    = f >> 7;
    const int rem  = f & 127;
    const int nsub = rem >> 5;
    const int ks   = rem & 31;
    const int lane = threadIdx.x;
    const int quad = lane >> 4, l4 = lane & 15;
    const float* W = (p == 0) ? Wk : (p == 1) ? Wv : Wq;
    const int n = nsub * 16 + l4;

    bf16x8 h, l;
#pragma unroll
    for (int j = 0; j < 8; ++j) {
        const int k = ks * 32 + quad * 8 + j;
        const unsigned hl = split_rtn(W[k * DD + n]);
        h[j] = (short)(hl & 0xFFFFu);
        l[j] = (short)(hl >> 16);
    }
    ((bf16x8*)bwh)[f * 64 + lane] = h;
    ((bf16x8*)bwl)[f * 64 + lane] = l;
}

// ---------------------------------------------------------------------------
// Kernel 2: FUSED x-split + projection MFMA, ALL-P PER BLOCK (r8).
// 256 blocks x 512 threads (8 waves), block = mt. Phase A stages/splits the
// 16x1024 x-tile ONCE (was 3x in r6): thread (half=tid>>8, col k=(tid&255)*4)
// covers 8 rows; identical split_rtn values + swizzled LDS layout as r4-r6.
// Phase B: 12 (p,nsub) units on 8 waves — wave w does unit u=w, waves 0-3
// also u=8+w. Unit body (MFMA chain + epilogue) byte-identical to r6 ->
// bit-identical outputs. x HBM reads 48->16 MB, split VALU /3, no LDS tail.
// ---------------------------------------------------------------------------
__global__ __launch_bounds__(512) void proj_fused_kernel(
    const float* __restrict__ x,
    const unsigned short* __restrict__ bwh,
    const unsigned short* __restrict__ bwl,
    float* __restrict__ kT,     // [DD][NROWP] padded
    float* __restrict__ vbuf,   // [NROW][DD]
    float* __restrict__ qbuf)   // [BB*TT][DD]
{
    __shared__ __align__(16) unsigned short lh[16 * 1024];   // 32 KB hi plane
    __shared__ __align__(16) unsigned short ll[16 * 1024];   // 32 KB lo plane

    const int mt   = blockIdx.x;        // 0..255
    const int bs0  = mt * 16;
    const int tid  = threadIdx.x;       // 0..511

    // ---- phase A: stage + split x tile (once per mt) ----
    {
        const int k  = (tid & 255) * 4;     // 0..1020
        const int r0 = (tid >> 8) * 8;      // rows 0-7 or 8-15
#pragma unroll 4
        for (int ii = 0; ii < 8; ++ii) {
            const int i = r0 + ii;
            int arow = bs0 + i; if (arow > NROW - 1) arow = NROW - 1;  // pad clamp
            const f4 xv = *(const f4*)(x + (size_t)arow * CC + k);
            s4 h, l;
#pragma unroll
            for (int j = 0; j < 4; ++j) {
                const unsigned hl = split_rtn(xv[j]);
                h[j] = (short)(hl & 0xFFFFu);
                l[j] = (short)(hl >> 16);
            }
            const int idx = i * 1024 + (k ^ ((i & 7) << 3));
            *(s4*)&lh[idx] = h;
            *(s4*)&ll[idx] = l;
        }
    }
    __syncthreads();

    // ---- phase B: 12 MFMA units on 8 waves ----
    const int lane = tid & 63;
    const int w    = tid >> 6;          // wave 0..7
    const int quad = lane >> 4, l4 = lane & 15;
    const int rbase = l4 * 1024;
    const int kxor  = (l4 & 7) << 3;

#pragma unroll
    for (int pass = 0; pass < 2; ++pass) {
        if (pass == 1 && w >= 4) break;
        const int u    = (pass == 0) ? w : (8 + w);   // unit 0..11
        const int p    = u >> 2;
        const int nsub = u & 3;

        const bf16x8* bh = (const bf16x8*)bwh + (size_t)(u * 32) * 64 + lane;
        const bf16x8* bl = (const bf16x8*)bwl + (size_t)(u * 32) * 64 + lane;

        f32x4 acc = {0.f, 0.f, 0.f, 0.f};
#pragma unroll 4
        for (int ks = 0; ks < 32; ++ks) {
            const int k0 = ks * 32 + quad * 8;
            const bf16x8 ah = *(const bf16x8*)&lh[rbase + (k0 ^ kxor)];
            const bf16x8 al = *(const bf16x8*)&ll[rbase + (k0 ^ kxor)];
            const bf16x8 bhn = bh[ks * 64];
            const bf16x8 bln = bl[ks * 64];
            acc = __builtin_amdgcn_mfma_f32_16x16x32_bf16(ah, bhn, acc, 0, 0, 0);
            acc = __builtin_amdgcn_mfma_f32_16x16x32_bf16(ah, bln, acc, 0, 0, 0);
            acc = __builtin_amdgcn_mfma_f32_16x16x32_bf16(al, bhn, acc, 0, 0, 0);
            acc = __builtin_amdgcn_mfma_f32_16x16x32_bf16(al, bln, acc, 0, 0, 0);
        }

        // ---- epilogue: D[row=quad*4+reg][col=l4], d = nsub*16 + l4 ----
        const int d = nsub * 16 + l4;
#pragma unroll
        for (int reg = 0; reg < 4; ++reg) {
            const int bs = bs0 + quad * 4 + reg;
            if (bs < NROW) {
                const float val = acc[reg];
                const int b = bs / SS, ss = bs - b * SS;
                if (p == 0) {
                    kT[(size_t)d * NROWP + b * 1024 + ss] = val;   // padded
                } else if (p == 1) {
                    vbuf[(size_t)bs * DD + d] = val;
                } else {
                    if (ss >= TT - 1)
                        qbuf[((size_t)b * TT + (ss - (TT - 1))) * DD + d] = val;
                }
            }
        }
    }
}

// ---------------------------------------------------------------------------
// Kernel 3: attention, WT=8 windows/block, 256 blocks x 512 threads.
// (verified r6 — unchanged)
// ---------------------------------------------------------------------------
__global__ __launch_bounds__(512) void attn_kernel(
    const float* __restrict__ kT,     // [DD][NROWP] padded
    const float* __restrict__ vbuf,   // [NROW][DD]
    const float* __restrict__ qbuf,   // [BB*TT][DD]
    const float* __restrict__ bias,   // [DD][TT]
    float* __restrict__ out)          // [BB*TT][DD]
{
    __shared__ __align__(16) float qsT[DD][8];       // [d][m]    2 KB
    __shared__ __align__(8) float part[2][8][TT];    // [h][m][t] 32 KB
    __shared__ float weiT[TT][9];                    // [t][m] padded, 18 KB
    __shared__ float invs[8];
    __shared__ float partial[8][8][DD];              // 16 KB

    const int tid  = threadIdx.x;
    const int lane = tid & 63;
    const int wv   = tid >> 6;          // 0..7
    const int blk  = blockIdx.x;        // 0..255
    const int b    = blk >> 6;
    const int w0   = (blk & 63) * 8;

    if (tid < 8 * DD) {                 // all 512 threads
        const int m = tid >> 6, dd = tid & 63;
        qsT[dd][m] = qbuf[((size_t)b * TT + w0 + m) * DD + dd];
    }
    __syncthreads();

    // ---- phase 1: q.k (banded) + q.bias; 16 logits/thread ----
    {
        const int h = tid >> 8, p = tid & 255;
        const int t0 = 2 * p;
        const float* kcol = kT + (size_t)(32 * h) * NROWP + b * 1024 + w0 + t0;
        const float* bp   = bias + (size_t)(32 * h) * TT + t0;
        float am[8][2];
#pragma unroll
        for (int m = 0; m < 8; ++m) { am[m][0] = 0.f; am[m][1] = 0.f; }
#pragma unroll 4
        for (int i = 0; i < 32; ++i) {
            const float* kr = kcol + (size_t)i * NROWP;
            const f2 k01 = *(const f2*)kr;
            const f2 k23 = *(const f2*)(kr + 2);
            const f2 k45 = *(const f2*)(kr + 4);
            const f2 k67 = *(const f2*)(kr + 6);
            const float k8 = kr[8];
            const f2 bv = *(const f2*)(bp + (size_t)i * TT);
            const f4 qA = *(const f4*)&qsT[32 * h + i][0];
            const f4 qB = *(const f4*)&qsT[32 * h + i][4];
            const float kk[9] = {k01[0], k01[1], k23[0], k23[1],
                                 k45[0], k45[1], k67[0], k67[1], k8};
            const float qq[8] = {qA[0], qA[1], qA[2], qA[3],
                                 qB[0], qB[1], qB[2], qB[3]};
#pragma unroll
            for (int m = 0; m < 8; ++m) {
                // per-logit chain: k-fma then bias-fma (verified r5 order)
                am[m][0] = fmaf(qq[m], kk[m],     am[m][0]);
                am[m][0] = fmaf(qq[m], bv[0],     am[m][0]);
                am[m][1] = fmaf(qq[m], kk[m + 1], am[m][1]);
                am[m][1] = fmaf(qq[m], bv[1],     am[m][1]);
            }
        }
#pragma unroll
        for (int m = 0; m < 8; ++m)
            *(f2*)&part[h][m][t0] = (f2){am[m][0], am[m][1]};
    }
    __syncthreads();

    // ---- softmax: wave wv owns window m = wv; 8 t per lane ----
    {
        const int m = wv;
        float r[8];
#pragma unroll
        for (int j = 0; j < 8; ++j) {
            const int t = lane + 64 * j;
            r[j] = part[0][m][t] + part[1][m][t];
        }
        float mx = r[0];
#pragma unroll
        for (int j = 1; j < 8; ++j) mx = fmaxf(mx, r[j]);
#pragma unroll
        for (int off = 1; off < 64; off <<= 1)
            mx = fmaxf(mx, __shfl_xor(mx, off, 64));
        float sum = 0.f;
#pragma unroll
        for (int j = 0; j < 8; ++j) {
            const float e = __expf(r[j] - mx);
            weiT[lane + 64 * j][m] = e;
            sum += e;
        }
#pragma unroll
        for (int off = 1; off < 64; off <<= 1)
            sum += __shfl_xor(sum, off, 64);
        if (lane == 0) invs[m] = 1.f / sum;
    }
    __syncthreads();

    // ---- phase 2: PV, wave wv covers 64 t, sliding 8-reg v window ----
    {
        const int t0r = wv * 64;
        const float* vb = vbuf + ((size_t)b * SS + w0 + t0r) * DD + lane;
        float pm[8];
#pragma unroll
        for (int m = 0; m < 8; ++m) pm[m] = 0.f;
        float vv[8];
#pragma unroll
        for (int m = 0; m < 7; ++m) vv[m] = vb[(size_t)m * DD];
#pragma unroll 2
        for (int t = 0; t < 64; ++t) {
            vv[7] = vb[(size_t)(t + 7) * DD];
            const float* wt = &weiT[t0r + t][0];   // wave-uniform -> broadcast
#pragma unroll
            for (int m = 0; m < 8; ++m)
                pm[m] = fmaf(wt[m], vv[m], pm[m]);
#pragma unroll
            for (int m = 0; m < 7; ++m) vv[m] = vv[m + 1];
        }
#pragma unroll
        for (int m = 0; m < 8; ++m)
            partial[wv][m][lane] = pm[m];
    }
    __syncthreads();

    // ---- final reduce + store ----
    {
        const int m = tid >> 6, dd = tid & 63;
        float o = 0.f;
#pragma unroll
        for (int j = 0; j < 8; ++j) o += partial[j][m][dd];
        out[((size_t)b * TT + w0 + m) * DD + dd] = o * invs[m];
    }
}

// ---------------------------------------------------------------------------
extern "C" void kernel_launch(void* const* d_in, const int* in_sizes, int n_in,
                              void* d_out, int out_size, void* d_ws, size_t ws_size,
                              hipStream_t stream) {
    const float* x    = (const float*)d_in[0];
    const float* Wk   = (const float*)d_in[1];
    const float* Wv   = (const float*)d_in[2];
    const float* Wq   = (const float*)d_in[3];
    const float* bias = (const float*)d_in[4];
    float* out = (float*)d_out;

    char* ws = (char*)d_ws;
    float* kT             = (float*)(ws + 0);                 // 1 MB
    float* vbuf           = (float*)(ws + (2u  << 20));       // 1.05 MB
    float* qbuf           = (float*)(ws + (4u  << 20));       // 0.52 MB
    unsigned short* bwh   = (unsigned short*)(ws + (6u  << 20));  // 0.39 MB
    unsigned short* bwl   = (unsigned short*)(ws + (8u  << 20));  // 0.39 MB

    wsplit_kernel<<<384, 64, 0, stream>>>(Wk, Wv, Wq, bwh, bwl);
    proj_fused_kernel<<<256, 512, 0, stream>>>(x, bwh, bwl, kT, vbuf, qbuf);
    attn_kernel<<<BB * TT / 8, 512, 0, stream>>>(kT, vbuf, qbuf, bias, out);
}

// Round 9
// 104.199 us; speedup vs baseline: 2.4877x; 1.0059x over previous
//
#include <hip/hip_runtime.h>
#include <hip/hip_bf16.h>

#define BB 4      // batch
#define SS 1023   // source length = 2T-1
#define TT 512    // window length
#define CC 1024   // embed dim
#define DD 64     // head size
#define NROW (BB*SS)    // 4092
#define NROWP 4096      // padded kT row stride: kT[d][b*1024 + s]

typedef float f4 __attribute__((ext_vector_type(4)));
typedef float f2 __attribute__((ext_vector_type(2)));
typedef short bf16x8 __attribute__((ext_vector_type(8)));
typedef short s4 __attribute__((ext_vector_type(4)));
typedef float f32x4 __attribute__((ext_vector_type(4)));

// RTN bf16 split: v ~= hi + lo (packed u32 lo<<16|hi).
// SESSION INVARIANT: this split + ALL FOUR MFMA products is the only
// verified-passing config (r12/r13: 0.0156). Manual trunc/half-up splits
// with al*bl dropped fail deterministically at ~0.18 (r14/r15/r16) for
// reasons not visible at source level. Do not "optimize" this again.
// SESSION NOTE r7: cooperative grid.sync() costs ~75us/sync at grid=256 on
// this chip (mega-kernel: 176us, VALUBusy 5.9%). Never fuse via grid.sync.
__device__ __forceinline__ unsigned split_rtn(float v) {
    const unsigned u  = __builtin_bit_cast(unsigned, v);
    const unsigned r  = u + 0x7FFFu + ((u >> 16) & 1u);
    const unsigned hi = r >> 16;
    const float hif   = __builtin_bit_cast(float, r & 0xFFFF0000u);
    const float res   = v - hif;
    const unsigned u2 = __builtin_bit_cast(unsigned, res);
    const unsigned r2 = u2 + 0x7FFFu + ((u2 >> 16) & 1u);
    return (r2 & 0xFFFF0000u) | hi;                    // lo<<16 | hi
}

// ---------------------------------------------------------------------------
// Kernel 1: split W{k,v,q} into B-fragment-ordered bf16 hi/lo (RTN).
// (verified r4-r8 — unchanged)
// ---------------------------------------------------------------------------
__global__ __launch_bounds__(64) void wsplit_kernel(
    const float* __restrict__ Wk,
    const float* __restrict__ Wv,
    const float* __restrict__ Wq,
    unsigned short* __restrict__ bwh,
    unsigned short* __restrict__ bwl)
{
    const int f    = blockIdx.x;        // 0..383
    const int p    = f >> 7;
    const int rem  = f & 127;
    const int nsub = rem >> 5;
    const int ks   = rem & 31;
    const int lane = threadIdx.x;
    const int quad = lane >> 4, l4 = lane & 15;
    const float* W = (p == 0) ? Wk : (p == 1) ? Wv : Wq;
    const int n = nsub * 16 + l4;

    bf16x8 h, l;
#pragma unroll
    for (int j = 0; j < 8; ++j) {
        const int k = ks * 32 + quad * 8 + j;
        const unsigned hl = split_rtn(W[k * DD + n]);
        h[j] = (short)(hl & 0xFFFFu);
        l[j] = (short)(hl >> 16);
    }
    ((bf16x8*)bwh)[f * 64 + lane] = h;
    ((bf16x8*)bwl)[f * 64 + lane] = l;
}

// ---------------------------------------------------------------------------
// Kernel 2: FUSED x-split + projection MFMA, 2D GEMM RETILE (r9).
// 256 blocks x 512 threads, block = (rt=blk>>1 [32-row tile], cg=blk&1
// [6-unit col group]). Phase A stages/splits the 32x1024 x stripe into
// 128 KB swizzled LDS (each stripe staged by 2 blocks -> x read 2x, L3-hot;
// bw reads HALVED vs r8: each block reads only its 6 units = 393 KB,
// 100 MB total). Phase B: 12 wave-tasks (rh,ucol) on 8 waves — wave w does
// task w, waves 0-3 also task 8+w. Per-unit MFMA chain + epilogue
// byte-identical to r8 -> bit-identical outputs. LDS 128KB -> 1 block/CU.
// ---------------------------------------------------------------------------
__global__ __launch_bounds__(512) void proj_fused_kernel(
    const float* __restrict__ x,
    const unsigned short* __restrict__ bwh,
    const unsigned short* __restrict__ bwl,
    float* __restrict__ kT,     // [DD][NROWP] padded
    float* __restrict__ vbuf,   // [NROW][DD]
    float* __restrict__ qbuf)   // [BB*TT][DD]
{
    __shared__ __align__(16) unsigned short lh[32 * 1024];   // 64 KB hi plane
    __shared__ __align__(16) unsigned short ll[32 * 1024];   // 64 KB lo plane

    const int rt   = blockIdx.x >> 1;   // 0..127, 32-row tile
    const int cg   = blockIdx.x & 1;    // 0..1, 6-unit col group
    const int tid  = threadIdx.x;       // 0..511

    // ---- phase A: stage + split 32x1024 x stripe (same split values) ----
    {
        const int k  = (tid & 255) * 4;     // 0..1020
        const int r0 = (tid >> 8) * 16;     // rows 0-15 or 16-31
#pragma unroll 4
        for (int ii = 0; ii < 16; ++ii) {
            const int i = r0 + ii;          // 0..31
            int arow = rt * 32 + i; if (arow > NROW - 1) arow = NROW - 1;
            const f4 xv = *(const f4*)(x + (size_t)arow * CC + k);
            s4 h, l;
#pragma unroll
            for (int j = 0; j < 4; ++j) {
                const unsigned hl = split_rtn(xv[j]);
                h[j] = (short)(hl & 0xFFFFu);
                l[j] = (short)(hl >> 16);
            }
            const int idx = i * 1024 + (k ^ ((i & 7) << 3));
            *(s4*)&lh[idx] = h;
            *(s4*)&ll[idx] = l;
        }
    }
    __syncthreads();

    // ---- phase B: 12 wave-tasks (rh = 16-row half, ucol = unit in group) --
    const int lane = tid & 63;
    const int w    = tid >> 6;          // wave 0..7
    const int quad = lane >> 4, l4 = lane & 15;
    const int kxor = (l4 & 7) << 3;

#pragma unroll
    for (int pass = 0; pass < 2; ++pass) {
        if (pass == 1 && w >= 4) break;
        const int tt   = (pass == 0) ? w : (8 + w);   // task 0..11
        const int ucol = tt % 6;
        const int rh   = tt / 6;
        const int ug   = cg * 6 + ucol;               // global unit 0..11
        const int p    = ug >> 2;
        const int nsub = ug & 3;
        const int bs0  = rt * 32 + rh * 16;
        const int rbase = (rh * 16 + l4) * 1024;

        const bf16x8* bh = (const bf16x8*)bwh + (size_t)(ug * 32) * 64 + lane;
        const bf16x8* bl = (const bf16x8*)bwl + (size_t)(ug * 32) * 64 + lane;

        f32x4 acc = {0.f, 0.f, 0.f, 0.f};
#pragma unroll 4
        for (int ks = 0; ks < 32; ++ks) {
            const int k0 = ks * 32 + quad * 8;
            const bf16x8 ah = *(const bf16x8*)&lh[rbase + (k0 ^ kxor)];
            const bf16x8 al = *(const bf16x8*)&ll[rbase + (k0 ^ kxor)];
            const bf16x8 bhn = bh[ks * 64];
            const bf16x8 bln = bl[ks * 64];
            acc = __builtin_amdgcn_mfma_f32_16x16x32_bf16(ah, bhn, acc, 0, 0, 0);
            acc = __builtin_amdgcn_mfma_f32_16x16x32_bf16(ah, bln, acc, 0, 0, 0);
            acc = __builtin_amdgcn_mfma_f32_16x16x32_bf16(al, bhn, acc, 0, 0, 0);
            acc = __builtin_amdgcn_mfma_f32_16x16x32_bf16(al, bln, acc, 0, 0, 0);
        }

        // ---- epilogue: D[row=quad*4+reg][col=l4], d = nsub*16 + l4 ----
        const int d = nsub * 16 + l4;
#pragma unroll
        for (int reg = 0; reg < 4; ++reg) {
            const int bs = bs0 + quad * 4 + reg;
            if (bs < NROW) {
                const float val = acc[reg];
                const int b = bs / SS, ss = bs - b * SS;
                if (p == 0) {
                    kT[(size_t)d * NROWP + b * 1024 + ss] = val;   // padded
                } else if (p == 1) {
                    vbuf[(size_t)bs * DD + d] = val;
                } else {
                    if (ss >= TT - 1)
                        qbuf[((size_t)b * TT + (ss - (TT - 1))) * DD + d] = val;
                }
            }
        }
    }
}

// ---------------------------------------------------------------------------
// Kernel 3: attention, WT=8 windows/block, 256 blocks x 512 threads.
// (verified r6/r8 — unchanged)
// ---------------------------------------------------------------------------
__global__ __launch_bounds__(512) void attn_kernel(
    const float* __restrict__ kT,     // [DD][NROWP] padded
    const float* __restrict__ vbuf,   // [NROW][DD]
    const float* __restrict__ qbuf,   // [BB*TT][DD]
    const float* __restrict__ bias,   // [DD][TT]
    float* __restrict__ out)          // [BB*TT][DD]
{
    __shared__ __align__(16) float qsT[DD][8];       // [d][m]    2 KB
    __shared__ __align__(8) float part[2][8][TT];    // [h][m][t] 32 KB
    __shared__ float weiT[TT][9];                    // [t][m] padded, 18 KB
    __shared__ float invs[8];
    __shared__ float partial[8][8][DD];              // 16 KB

    const int tid  = threadIdx.x;
    const int lane = tid & 63;
    const int wv   = tid >> 6;          // 0..7
    const int blk  = blockIdx.x;        // 0..255
    const int b    = blk >> 6;
    const int w0   = (blk & 63) * 8;

    if (tid < 8 * DD) {                 // all 512 threads
        const int m = tid >> 6, dd = tid & 63;
        qsT[dd][m] = qbuf[((size_t)b * TT + w0 + m) * DD + dd];
    }
    __syncthreads();

    // ---- phase 1: q.k (banded) + q.bias; 16 logits/thread ----
    {
        const int h = tid >> 8, p = tid & 255;
        const int t0 = 2 * p;
        const float* kcol = kT + (size_t)(32 * h) * NROWP + b * 1024 + w0 + t0;
        const float* bp   = bias + (size_t)(32 * h) * TT + t0;
        float am[8][2];
#pragma unroll
        for (int m = 0; m < 8; ++m) { am[m][0] = 0.f; am[m][1] = 0.f; }
#pragma unroll 4
        for (int i = 0; i < 32; ++i) {
            const float* kr = kcol + (size_t)i * NROWP;
            const f2 k01 = *(const f2*)kr;
            const f2 k23 = *(const f2*)(kr + 2);
            const f2 k45 = *(const f2*)(kr + 4);
            const f2 k67 = *(const f2*)(kr + 6);
            const float k8 = kr[8];
            const f2 bv = *(const f2*)(bp + (size_t)i * TT);
            const f4 qA = *(const f4*)&qsT[32 * h + i][0];
            const f4 qB = *(const f4*)&qsT[32 * h + i][4];
            const float kk[9] = {k01[0], k01[1], k23[0], k23[1],
                                 k45[0], k45[1], k67[0], k67[1], k8};
            const float qq[8] = {qA[0], qA[1], qA[2], qA[3],
                                 qB[0], qB[1], qB[2], qB[3]};
#pragma unroll
            for (int m = 0; m < 8; ++m) {
                // per-logit chain: k-fma then bias-fma (verified r5 order)
                am[m][0] = fmaf(qq[m], kk[m],     am[m][0]);
                am[m][0] = fmaf(qq[m], bv[0],     am[m][0]);
                am[m][1] = fmaf(qq[m], kk[m + 1], am[m][1]);
                am[m][1] = fmaf(qq[m], bv[1],     am[m][1]);
            }
        }
#pragma unroll
        for (int m = 0; m < 8; ++m)
            *(f2*)&part[h][m][t0] = (f2){am[m][0], am[m][1]};
    }
    __syncthreads();

    // ---- softmax: wave wv owns window m = wv; 8 t per lane ----
    {
        const int m = wv;
        float r[8];
#pragma unroll
        for (int j = 0; j < 8; ++j) {
            const int t = lane + 64 * j;
            r[j] = part[0][m][t] + part[1][m][t];
        }
        float mx = r[0];
#pragma unroll
        for (int j = 1; j < 8; ++j) mx = fmaxf(mx, r[j]);
#pragma unroll
        for (int off = 1; off < 64; off <<= 1)
            mx = fmaxf(mx, __shfl_xor(mx, off, 64));
        float sum = 0.f;
#pragma unroll
        for (int j = 0; j < 8; ++j) {
            const float e = __expf(r[j] - mx);
            weiT[lane + 64 * j][m] = e;
            sum += e;
        }
#pragma unroll
        for (int off = 1; off < 64; off <<= 1)
            sum += __shfl_xor(sum, off, 64);
        if (lane == 0) invs[m] = 1.f / sum;
    }
    __syncthreads();

    // ---- phase 2: PV, wave wv covers 64 t, sliding 8-reg v window ----
    {
        const int t0r = wv * 64;
        const float* vb = vbuf + ((size_t)b * SS + w0 + t0r) * DD + lane;
        float pm[8];
#pragma unroll
        for (int m = 0; m < 8; ++m) pm[m] = 0.f;
        float vv[8];
#pragma unroll
        for (int m = 0; m < 7; ++m) vv[m] = vb[(size_t)m * DD];
#pragma unroll 2
        for (int t = 0; t < 64; ++t) {
            vv[7] = vb[(size_t)(t + 7) * DD];
            const float* wt = &weiT[t0r + t][0];   // wave-uniform -> broadcast
#pragma unroll
            for (int m = 0; m < 8; ++m)
                pm[m] = fmaf(wt[m], vv[m], pm[m]);
#pragma unroll
            for (int m = 0; m < 7; ++m) vv[m] = vv[m + 1];
        }
#pragma unroll
        for (int m = 0; m < 8; ++m)
            partial[wv][m][lane] = pm[m];
    }
    __syncthreads();

    // ---- final reduce + store ----
    {
        const int m = tid >> 6, dd = tid & 63;
        float o = 0.f;
#pragma unroll
        for (int j = 0; j < 8; ++j) o += partial[j][m][dd];
        out[((size_t)b * TT + w0 + m) * DD + dd] = o * invs[m];
    }
}

// ---------------------------------------------------------------------------
extern "C" void kernel_launch(void* const* d_in, const int* in_sizes, int n_in,
                              void* d_out, int out_size, void* d_ws, size_t ws_size,
                              hipStream_t stream) {
    const float* x    = (const float*)d_in[0];
    const float* Wk   = (const float*)d_in[1];
    const float* Wv   = (const float*)d_in[2];
    const float* Wq   = (const float*)d_in[3];
    const float* bias = (const float*)d_in[4];
    float* out = (float*)d_out;

    char* ws = (char*)d_ws;
    float* kT             = (float*)(ws + 0);                 // 1 MB
    float* vbuf           = (float*)(ws + (2u  << 20));       // 1.05 MB
    float* qbuf           = (float*)(ws + (4u  << 20));       // 0.52 MB
    unsigned short* bwh   = (unsigned short*)(ws + (6u  << 20));  // 0.39 MB
    unsigned short* bwl   = (unsigned short*)(ws + (8u  << 20));  // 0.39 MB

    wsplit_kernel<<<384, 64, 0, stream>>>(Wk, Wv, Wq, bwh, bwl);
    proj_fused_kernel<<<256, 512, 0, stream>>>(x, bwh, bwl, kT, vbuf, qbuf);
    attn_kernel<<<BB * TT / 8, 512, 0, stream>>>(kT, vbuf, qbuf, bias, out);
}